// Round 1
// baseline (50.505 us; speedup 1.0000x reference)
//
#include <hip/hip_runtime.h>
#include <math.h>

// DescGroupPoolandNorm (pool='shift', candidate='top1', norm='l2')
//   B=4, K=8192, CG=1024, G=8, C=128
//   s = argmax over g of desc[b,k, 0*G+g]  (first channel group, first-wins)
//   out[b,k, c*G+g] = desc[b,k, c*G + (g+s)%G] / (||desc[b,k,:]||_2 + 1e-6)
//   kpts passes through.
// L2 norm is permutation-invariant -> single pass over the row.

#define NGRP 8
#define ROWLEN 1024  // CG

// Roll an 8-element group (held as two float4) left by compile-time S,
// scale by inv. Compile-time indices keep everything in registers.
template<int S>
__device__ __forceinline__ void roll_pair(const float4 a0, const float4 a1,
                                          const float inv,
                                          float4& o0, float4& o1) {
    const float f[8] = {a0.x, a0.y, a0.z, a0.w, a1.x, a1.y, a1.z, a1.w};
    o0.x = f[(S + 0) & 7] * inv;
    o0.y = f[(S + 1) & 7] * inv;
    o0.z = f[(S + 2) & 7] * inv;
    o0.w = f[(S + 3) & 7] * inv;
    o1.x = f[(S + 4) & 7] * inv;
    o1.y = f[(S + 5) & 7] * inv;
    o1.z = f[(S + 6) & 7] * inv;
    o1.w = f[(S + 7) & 7] * inv;
}

#define ROLL_CASE(S)                                                 \
    case S:                                                          \
        roll_pair<S>(a0, a1, inv, o0, o1);                           \
        roll_pair<S>(b0, b1, inv, o2, o3);                           \
        break;

__global__ __launch_bounds__(256) void REDFM_15676630630653_kernel(
    const float* __restrict__ desc, float* __restrict__ out, int rows) {
    const int gtid = blockIdx.x * 256 + threadIdx.x;
    const int r = gtid >> 6;          // one wave per row
    const int lane = threadIdx.x & 63;
    if (r >= rows) return;

    const float4* __restrict__ row = (const float4*)(desc + (size_t)r * ROWLEN);
    float4* __restrict__ orow = (float4*)(out + (size_t)r * ROWLEN);

    // Lane owns two full 8-float groups: group `lane` and group `lane+64`.
    const float4 a0 = row[2 * lane];
    const float4 a1 = row[2 * lane + 1];
    const float4 b0 = row[2 * lane + 128];
    const float4 b1 = row[2 * lane + 129];

    // Sum of squares of the 16 owned floats, then wave-wide reduce.
    float ss = a0.x * a0.x + a0.y * a0.y + a0.z * a0.z + a0.w * a0.w
             + a1.x * a1.x + a1.y * a1.y + a1.z * a1.z + a1.w * a1.w
             + b0.x * b0.x + b0.y * b0.y + b0.z * b0.z + b0.w * b0.w
             + b1.x * b1.x + b1.y * b1.y + b1.z * b1.z + b1.w * b1.w;
#pragma unroll
    for (int off = 1; off < 64; off <<= 1) ss += __shfl_xor(ss, off);
    const float inv = 1.0f / (sqrtf(ss) + 1e-6f);

    // argmax (first-wins) of row elements 0..7 — lane 0 owns them (a0,a1).
    const float vals[8] = {a0.x, a0.y, a0.z, a0.w, a1.x, a1.y, a1.z, a1.w};
    int bi = 0;
    float bv = vals[0];
#pragma unroll
    for (int m = 1; m < 8; m++) {
        if (vals[m] > bv) { bv = vals[m]; bi = m; }
    }
    // Broadcast lane 0's result; readfirstlane also marks it wave-uniform
    // (SGPR) so the switch below becomes a scalar branch.
    const int s = __builtin_amdgcn_readfirstlane(bi);

    float4 o0, o1, o2, o3;
    switch (s) {
        ROLL_CASE(0)
        ROLL_CASE(1)
        ROLL_CASE(2)
        ROLL_CASE(3)
        ROLL_CASE(4)
        ROLL_CASE(5)
        ROLL_CASE(6)
        ROLL_CASE(7)
        default: o0 = o1 = o2 = o3 = make_float4(0.f, 0.f, 0.f, 0.f); break;
    }

    orow[2 * lane] = o0;
    orow[2 * lane + 1] = o1;
    orow[2 * lane + 128] = o2;
    orow[2 * lane + 129] = o3;
}

extern "C" void kernel_launch(void* const* d_in, const int* in_sizes, int n_in,
                              void* d_out, int out_size, void* d_ws, size_t ws_size,
                              hipStream_t stream) {
    const float* kpts = (const float*)d_in[0];
    const float* desc = (const float*)d_in[1];
    float* out = (float*)d_out;

    const int kpts_elems = in_sizes[0];            // B*K*2 = 65536
    const int desc_elems = in_sizes[1];            // B*K*CG = 33554432
    const int rows = desc_elems / ROWLEN;          // B*K = 32768

    // Output layout: [kpts (pass-through) | normalized rolled desc]
    hipMemcpyAsync(out, kpts, (size_t)kpts_elems * sizeof(float),
                   hipMemcpyDeviceToDevice, stream);

    float* desc_out = out + kpts_elems;
    const int total_threads = rows * 64;           // one wave per row
    const int blocks = (total_threads + 255) / 256;
    REDFM_15676630630653_kernel<<<blocks, 256, 0, stream>>>(desc, desc_out, rows);
}